// Round 15
// baseline (518.234 us; speedup 1.0000x reference)
//
#include <hip/hip_runtime.h>

// Cvxpy_81174881894666: batched dual ascent (R15: 1024-thr, 32 A-floats/thread)
//   per batch b: 100 iters of
//     z = a^T lam;  y = sigmoid(-(c+z));  g = a y + b;  lam = max(lam+0.05 g, 0)
//   out: y = sigmoid(-(c + a^T lam_final)) [2048,256] f32, status int32 zeros.
//
// R14 post-mortem: MFMA split-bf16 failed numerically (absmax 0.64): the
// problem amplifies per-step error ~1e5x (R7 evidence), so 2^-16-level
// split-bf16 products -> O(1) final error. K-map concerns cancel (same map
// both operands); it's precision, not layout. MFMA path dead at useful cost.
// Back to VALU lineage (R11 = 454us). Root tax there: allocator shelves the
// 64-float A tile to AGPRs (~128 v_accvgpr_read/iter). R15: shrink per-thread
// tile UNDER the shelving threshold: 1024 thr/block, wave w owns rows
// [8w,8w+8), lane owns cols [4l,4l+4) -> 32 A-floats + ~28 working set ~ 60
// regs. LB(1024,4) caps VGPR at 128 (no pressure). Reduce tree: p[8] via
// swap32, swap16, xor8(dpp row_ror:8), + butterflies 4(swizzle),2,1(dpp).

#define BB 2048
#define MM 128
#define NN 256
#define NITER 100
#define STEP_ 0.05f

typedef unsigned int u32;
typedef u32 u32x2 __attribute__((ext_vector_type(2)));

__device__ __forceinline__ void plane32_swap(float& a, float& b) {
    u32x2 r = __builtin_amdgcn_permlane32_swap(__float_as_uint(a), __float_as_uint(b), false, false);
    a = __uint_as_float(r[0]);
    b = __uint_as_float(r[1]);
}
__device__ __forceinline__ void plane16_swap(float& a, float& b) {
    u32x2 r = __builtin_amdgcn_permlane16_swap(__float_as_uint(a), __float_as_uint(b), false, false);
    a = __uint_as_float(r[0]);
    b = __uint_as_float(r[1]);
}
__device__ __forceinline__ float dpp_xor1(float x) {   // quad_perm [1,0,3,2]
    return __int_as_float(__builtin_amdgcn_update_dpp(
        0, __float_as_int(x), 0xB1, 0xF, 0xF, true));
}
__device__ __forceinline__ float dpp_xor2(float x) {   // quad_perm [2,3,0,1]
    return __int_as_float(__builtin_amdgcn_update_dpp(
        0, __float_as_int(x), 0x4E, 0xF, 0xF, true));
}
__device__ __forceinline__ float dpp_xor8(float x) {   // row_ror:8 == xor8 in 16-row
    return __int_as_float(__builtin_amdgcn_update_dpp(
        0, __float_as_int(x), 0x128, 0xF, 0xF, true));
}

__global__ __launch_bounds__(1024, 4) void cvx_dual_ascent(
    const float* __restrict__ A,
    const float* __restrict__ Bv,
    const float* __restrict__ C,
    float* __restrict__ out)
{
    const int bi  = blockIdx.x;
    const int tid = threadIdx.x;     // 0..1023
    const int w   = tid >> 6;        // wave 0..15 -> rows [8w, 8w+8)
    const int l   = tid & 63;        // lane
    const int colq = l * 4;          // my 4 columns
    const int row8 = (l >> 3) & 7;   // row owned after g-reduce

    __shared__ float zp_s[16][260];  // z partials [wave][col]
    __shared__ float y_s[NN];
    __shared__ float lam_s[16][8];   // per-wave lambda (wave-private)

    // ---- load my 8 row-slices of A (read once), pin ----
    const float* Ab = A + (size_t)bi * (MM * NN);
    float4 areg[8];
    #pragma unroll
    for (int i = 0; i < 8; ++i)
        areg[i] = *reinterpret_cast<const float4*>(Ab + (8 * w + i) * NN + colq);
    #pragma unroll
    for (int i = 0; i < 8; ++i)
        asm volatile("" : "+v"(areg[i].x), "+v"(areg[i].y),
                          "+v"(areg[i].z), "+v"(areg[i].w));

    const float sb  = STEP_ * Bv[bi * MM + 8 * w + row8];  // 0.05*b for my row
    const int   col = tid >> 2;       // P2: 4 threads per column
    const int   h2  = tid & 3;
    const float c_r = C[bi * NN + col];
    float lam = 0.f;                  // lambda[my row], 8-replicated

    if (tid < 128) lam_s[tid >> 3][tid & 7] = 0.f;
    __syncthreads();

    for (int it = 0; it <= NITER; ++it) {
        // ---- P1: z partials for my 4 cols over my wave's 8 rows ----
        const float4 la = *reinterpret_cast<const float4*>(&lam_s[w][0]);
        const float4 lb = *reinterpret_cast<const float4*>(&lam_s[w][4]);
        float4 zpA = make_float4(0.f, 0.f, 0.f, 0.f);
        float4 zpB = make_float4(0.f, 0.f, 0.f, 0.f);
        zpA.x = fmaf(areg[0].x, la.x, zpA.x); zpA.y = fmaf(areg[0].y, la.x, zpA.y);
        zpA.z = fmaf(areg[0].z, la.x, zpA.z); zpA.w = fmaf(areg[0].w, la.x, zpA.w);
        zpA.x = fmaf(areg[1].x, la.y, zpA.x); zpA.y = fmaf(areg[1].y, la.y, zpA.y);
        zpA.z = fmaf(areg[1].z, la.y, zpA.z); zpA.w = fmaf(areg[1].w, la.y, zpA.w);
        zpA.x = fmaf(areg[2].x, la.z, zpA.x); zpA.y = fmaf(areg[2].y, la.z, zpA.y);
        zpA.z = fmaf(areg[2].z, la.z, zpA.z); zpA.w = fmaf(areg[2].w, la.z, zpA.w);
        zpA.x = fmaf(areg[3].x, la.w, zpA.x); zpA.y = fmaf(areg[3].y, la.w, zpA.y);
        zpA.z = fmaf(areg[3].z, la.w, zpA.z); zpA.w = fmaf(areg[3].w, la.w, zpA.w);
        zpB.x = fmaf(areg[4].x, lb.x, zpB.x); zpB.y = fmaf(areg[4].y, lb.x, zpB.y);
        zpB.z = fmaf(areg[4].z, lb.x, zpB.z); zpB.w = fmaf(areg[4].w, lb.x, zpB.w);
        zpB.x = fmaf(areg[5].x, lb.y, zpB.x); zpB.y = fmaf(areg[5].y, lb.y, zpB.y);
        zpB.z = fmaf(areg[5].z, lb.y, zpB.z); zpB.w = fmaf(areg[5].w, lb.y, zpB.w);
        zpB.x = fmaf(areg[6].x, lb.z, zpB.x); zpB.y = fmaf(areg[6].y, lb.z, zpB.y);
        zpB.z = fmaf(areg[6].z, lb.z, zpB.z); zpB.w = fmaf(areg[6].w, lb.z, zpB.w);
        zpB.x = fmaf(areg[7].x, lb.w, zpB.x); zpB.y = fmaf(areg[7].y, lb.w, zpB.y);
        zpB.z = fmaf(areg[7].z, lb.w, zpB.z); zpB.w = fmaf(areg[7].w, lb.w, zpB.w);
        *reinterpret_cast<float4*>(&zp_s[w][colq]) =
            make_float4(zpA.x + zpB.x, zpA.y + zpB.y,
                        zpA.z + zpB.z, zpA.w + zpB.w);
        __syncthreads();  // B1

        // ---- P2: z = sum over 16 waves; 4 threads per column (a quad) ----
        float z = zp_s[4 * h2 + 0][col] + zp_s[4 * h2 + 1][col]
                + zp_s[4 * h2 + 2][col] + zp_s[4 * h2 + 3][col];
        z += dpp_xor1(z);
        z += dpp_xor2(z);
        const float e = __expf(c_r + z);                    // v_exp-based
        const float y = __builtin_amdgcn_rcpf(1.0f + e);    // sigmoid(-(c+z))

        if (it == NITER) {                                  // uniform exit
            if (h2 == 0) out[(size_t)bi * NN + col] = y;
            break;
        }
        if (h2 == 0) y_s[col] = y;
        __syncthreads();  // B2

        // ---- P3: g for my wave's 8 rows (wave-local) ----
        const float4 y4 = *reinterpret_cast<const float4*>(&y_s[colq]);
        float p[8];
        #pragma unroll
        for (int k = 0; k < 8; ++k) {
            float acc =      areg[k].x * y4.x;
            acc = fmaf(areg[k].y, y4.y, acc);
            acc = fmaf(areg[k].z, y4.z, acc);
            p[k] = fmaf(areg[k].w, y4.w, acc);
        }
        // Round 1 (xor32): permlane32_swap + add -> q[4]; bit5 -> +4 rows.
        float q[4];
        #pragma unroll
        for (int k = 0; k < 4; ++k) {
            float a0 = p[k], b0 = p[k + 4];
            plane32_swap(a0, b0);
            q[k] = a0 + b0;
        }
        // Round 2 (xor16): permlane16_swap + add -> r[2]; bit4 -> +2 rows.
        float r2[2];
        #pragma unroll
        for (int k = 0; k < 2; ++k) {
            float a0 = q[k], b0 = q[k + 2];
            plane16_swap(a0, b0);
            r2[k] = a0 + b0;
        }
        // Round 3 (xor8, scrambled via DPP row_ror:8); bit3 -> +1 row.
        const bool b3 = (l & 8) != 0;
        float g;
        {
            const float keep = b3 ? r2[1] : r2[0];
            const float send = b3 ? r2[0] : r2[1];
            g = keep + dpp_xor8(send);
        }
        // Butterflies: xor4 (swizzle), xor2, xor1 (DPP).
        g += __shfl_xor(g, 4);
        g += dpp_xor2(g);
        g += dpp_xor1(g);
        lam = fmaxf(fmaf(STEP_, g, lam) + sb, 0.f);
        if ((l & 7) == 0) lam_s[w][row8] = lam;   // in-wave publish
        // no barrier: lam_s[w] read only by wave w (in-wave DS order)
    }

    if (tid == 0) out[(size_t)BB * NN + bi] = 0.0f;  // status[bi] = int32 0
}

extern "C" void kernel_launch(void* const* d_in, const int* in_sizes, int n_in,
                              void* d_out, int out_size, void* d_ws, size_t ws_size,
                              hipStream_t stream) {
    const float* A  = (const float*)d_in[0];  // [2048,128,256]
    const float* Bv = (const float*)d_in[1];  // [2048,128]
    const float* C  = (const float*)d_in[2];  // [2048,256]
    float* out = (float*)d_out;               // y [2048,256] f32 ++ status [2048]

    cvx_dual_ascent<<<dim3(BB), dim3(1024), 0, stream>>>(A, Bv, C, out);
}

// Round 19
// 517.864 us; speedup vs baseline: 1.0007x; 1.0007x over previous
//
#include <hip/hip_runtime.h>

// Cvxpy_81174881894666: batched dual ascent (R16: fit 8-wave/64-reg budget)
//   per batch b: 100 iters of
//     z = a^T lam;  y = sigmoid(-(c+z));  g = a y + b;  lam = max(lam+0.05 g, 0)
//   out: y = sigmoid(-(c + a^T lam_final)) [2048,256] f32, status int32 zeros.
//
// R15 post-mortem: RA shelved even the 32-float tile (VGPR=32, 88% occ,
// 518us) because demand (~66) exceeded the 64-reg/8-wave budget and its
// SEPARATE-FILE occupancy model thinks AGPRs are free. R16: shrink demand
// under 64 so shelving has zero payoff in both models:
//  - zp accumulator merged to one float4 (-4 regs; dep chain hidden at 8 waves)
//  - lambda read as 4x float2 windows (-6 regs, +2 inst)
//  - zp_s reads via one base pointer + imm offsets
//  - amdgpu_waves_per_eu(8): hard 64-reg budget; demand ~56-60 fits.
// Tell: VGPR_Count>=56 -> no shelf (expect ~300us); ~32 -> shelf persists.

#define BB 2048
#define MM 128
#define NN 256
#define NITER 100
#define STEP_ 0.05f

typedef unsigned int u32;
typedef u32 u32x2 __attribute__((ext_vector_type(2)));

__device__ __forceinline__ void plane32_swap(float& a, float& b) {
    u32x2 r = __builtin_amdgcn_permlane32_swap(__float_as_uint(a), __float_as_uint(b), false, false);
    a = __uint_as_float(r[0]);
    b = __uint_as_float(r[1]);
}
__device__ __forceinline__ void plane16_swap(float& a, float& b) {
    u32x2 r = __builtin_amdgcn_permlane16_swap(__float_as_uint(a), __float_as_uint(b), false, false);
    a = __uint_as_float(r[0]);
    b = __uint_as_float(r[1]);
}
__device__ __forceinline__ float dpp_xor1(float x) {   // quad_perm [1,0,3,2]
    return __int_as_float(__builtin_amdgcn_update_dpp(
        0, __float_as_int(x), 0xB1, 0xF, 0xF, true));
}
__device__ __forceinline__ float dpp_xor2(float x) {   // quad_perm [2,3,0,1]
    return __int_as_float(__builtin_amdgcn_update_dpp(
        0, __float_as_int(x), 0x4E, 0xF, 0xF, true));
}
__device__ __forceinline__ float dpp_xor8(float x) {   // row_ror:8 == xor8 in 16-row
    return __int_as_float(__builtin_amdgcn_update_dpp(
        0, __float_as_int(x), 0x128, 0xF, 0xF, true));
}

__global__ __attribute__((amdgpu_flat_work_group_size(1024, 1024),
                          amdgpu_waves_per_eu(8)))
void cvx_dual_ascent(
    const float* __restrict__ A,
    const float* __restrict__ Bv,
    const float* __restrict__ C,
    float* __restrict__ out)
{
    const int bi  = blockIdx.x;
    const int tid = threadIdx.x;     // 0..1023
    const int w   = tid >> 6;        // wave 0..15 -> rows [8w, 8w+8)
    const int l   = tid & 63;        // lane
    const int colq = l * 4;          // my 4 columns
    const int row8 = (l >> 3) & 7;   // row owned after g-reduce

    __shared__ float zp_s[16][260];  // z partials [wave][col]
    __shared__ float y_s[NN];
    __shared__ float lam_s[16][8];   // per-wave lambda (wave-private)

    // ---- load my 8 row-slices of A (read once), pin ----
    const float* Ab = A + (size_t)bi * (MM * NN);
    float4 areg[8];
    #pragma unroll
    for (int i = 0; i < 8; ++i)
        areg[i] = *reinterpret_cast<const float4*>(Ab + (8 * w + i) * NN + colq);
    #pragma unroll
    for (int i = 0; i < 8; ++i)
        asm volatile("" : "+v"(areg[i].x), "+v"(areg[i].y),
                          "+v"(areg[i].z), "+v"(areg[i].w));

    const float sb  = STEP_ * Bv[bi * MM + 8 * w + row8];  // 0.05*b for my row
    const int   col = tid >> 2;       // P2: 4 threads per column
    const int   h2  = tid & 3;
    const float c_r = C[bi * NN + col];
    float lam = 0.f;                  // lambda[my row], 8-replicated

    if (tid < 128) lam_s[tid >> 3][tid & 7] = 0.f;
    __syncthreads();

    for (int it = 0; it <= NITER; ++it) {
        // ---- P1: z partials; lambda via float2 windows, one accumulator ----
        float4 zp = make_float4(0.f, 0.f, 0.f, 0.f);
        #pragma unroll
        for (int k = 0; k < 4; ++k) {
            const float2 lp = *reinterpret_cast<const float2*>(&lam_s[w][2 * k]);
            zp.x = fmaf(areg[2*k].x, lp.x, zp.x);
            zp.y = fmaf(areg[2*k].y, lp.x, zp.y);
            zp.z = fmaf(areg[2*k].z, lp.x, zp.z);
            zp.w = fmaf(areg[2*k].w, lp.x, zp.w);
            zp.x = fmaf(areg[2*k+1].x, lp.y, zp.x);
            zp.y = fmaf(areg[2*k+1].y, lp.y, zp.y);
            zp.z = fmaf(areg[2*k+1].z, lp.y, zp.z);
            zp.w = fmaf(areg[2*k+1].w, lp.y, zp.w);
        }
        *reinterpret_cast<float4*>(&zp_s[w][colq]) = zp;
        __syncthreads();  // B1

        // ---- P2: z = sum over 16 waves; 4 threads per column (a quad) ----
        const float* bzp = &zp_s[4 * h2][col];
        float z = bzp[0] + bzp[260] + bzp[520] + bzp[780];
        z += dpp_xor1(z);
        z += dpp_xor2(z);
        const float e = __expf(c_r + z);                    // v_exp-based
        const float y = __builtin_amdgcn_rcpf(1.0f + e);    // sigmoid(-(c+z))

        if (it == NITER) {                                  // uniform exit
            if (h2 == 0) out[(size_t)bi * NN + col] = y;
            break;
        }
        if (h2 == 0) y_s[col] = y;
        __syncthreads();  // B2

        // ---- P3: g for my wave's 8 rows (wave-local) ----
        const float4 y4 = *reinterpret_cast<const float4*>(&y_s[colq]);
        float p[8];
        #pragma unroll
        for (int k = 0; k < 8; ++k) {
            float acc =      areg[k].x * y4.x;
            acc = fmaf(areg[k].y, y4.y, acc);
            acc = fmaf(areg[k].z, y4.z, acc);
            p[k] = fmaf(areg[k].w, y4.w, acc);
        }
        // Round 1 (xor32): permlane32_swap + add; bit5 -> +4 rows.
        float q0, q1;
        {
            float a0 = p[0], b0 = p[4]; plane32_swap(a0, b0);
            float a1 = p[1], b1 = p[5]; plane32_swap(a1, b1);
            float a2 = p[2], b2 = p[6]; plane32_swap(a2, b2);
            float a3 = p[3], b3v = p[7]; plane32_swap(a3, b3v);
            // Round 2 (xor16): permlane16_swap + add; bit4 -> +2 rows.
            float s0 = a0 + b0, s1 = a1 + b1, s2 = a2 + b2, s3 = a3 + b3v;
            float c0 = s0, d0 = s2; plane16_swap(c0, d0);
            float c1 = s1, d1 = s3; plane16_swap(c1, d1);
            q0 = c0 + d0;
            q1 = c1 + d1;
        }
        // Round 3 (xor8, scrambled via DPP row_ror:8); bit3 -> +1 row.
        const bool b3 = (l & 8) != 0;
        float g;
        {
            const float keep = b3 ? q1 : q0;
            const float send = b3 ? q0 : q1;
            g = keep + dpp_xor8(send);
        }
        // Butterflies: xor4 (swizzle), xor2, xor1 (DPP).
        g += __shfl_xor(g, 4);
        g += dpp_xor2(g);
        g += dpp_xor1(g);
        lam = fmaxf(fmaf(STEP_, g, lam) + sb, 0.f);
        if ((l & 7) == 0) lam_s[w][row8] = lam;   // in-wave publish
        // no barrier: lam_s[w] read only by wave w (in-wave DS order)
    }

    if (tid == 0) out[(size_t)BB * NN + bi] = 0.0f;  // status[bi] = int32 0
}

extern "C" void kernel_launch(void* const* d_in, const int* in_sizes, int n_in,
                              void* d_out, int out_size, void* d_ws, size_t ws_size,
                              hipStream_t stream) {
    const float* A  = (const float*)d_in[0];  // [2048,128,256]
    const float* Bv = (const float*)d_in[1];  // [2048,128]
    const float* C  = (const float*)d_in[2];  // [2048,256]
    float* out = (float*)d_out;               // y [2048,256] f32 ++ status [2048]

    cvx_dual_ascent<<<dim3(BB), dim3(1024), 0, stream>>>(A, Bv, C, out);
}

// Round 21
// 511.035 us; speedup vs baseline: 1.0141x; 1.0134x over previous
//
#include <hip/hip_runtime.h>

// Cvxpy_81174881894666: batched dual ascent (R21: mega-asm + TRANS hazard fix)
//   per batch b: 100 iters of
//     z = a^T lam;  y = sigmoid(-(c+z));  g = a y + b;  lam = max(lam+0.05 g, 0)
//   out: y = sigmoid(-(c + a^T lam_final)) [2048,256] f32, status int32 zeros.
//
// R20 post-mortem: absmax 202 ~ 1+e^(c+z) -> consumers of v_exp/v_rcp read
// the dst register before the TRANS result landed. CDNA trans ops need a
// manual wait state; the compiler's hazard recognizer inserts it in normal
// code but NOT inside asm blocks. R21: s_nop 1 after each v_exp_f32/v_rcp_f32
// before consumption; scc clobber; lgkmcnt(0) after lambda publish.
// Structure unchanged: A tile pinned in v[36:99] by the asm itself (kills the
// allocator's AGPR-shelving tax ~128 v_accvgpr_read/iter that bounded R7-R19).

#define BB 2048
#define MM 128
#define NN 256

__global__ __launch_bounds__(512, 2) void cvx_dual_ascent(
    const float* __restrict__ A,
    const float* __restrict__ Bv,
    const float* __restrict__ C,
    float* __restrict__ out)
{
    const int bi  = blockIdx.x;
    const int tid = threadIdx.x;
    const int w   = tid >> 6;          // wave 0..7 -> rows [16w,16w+16)
    const int l   = tid & 63;
    const int c   = tid >> 1;          // P2/out column (2 threads per col)
    const int myrow = (l >> 1) & 15;   // row owned after reduce

    __shared__ float zp_s[8][260];     // z partials [wave][col]
    __shared__ float y_s[NN];
    __shared__ float lam_s[8][16];     // per-wave lambda (wave-private)
    __shared__ float scr_s[512];       // lane^32 exchange scratch

    const float* Ab = A + (size_t)bi * (MM * NN);
    unsigned long long a0  = (unsigned long long)(Ab + (16*w + 0)  * NN + 4*l);
    unsigned long long a4  = (unsigned long long)(Ab + (16*w + 4)  * NN + 4*l);
    unsigned long long a8  = (unsigned long long)(Ab + (16*w + 8)  * NN + 4*l);
    unsigned long long a12 = (unsigned long long)(Ab + (16*w + 12) * NN + 4*l);
    unsigned lamrd = (unsigned)(size_t)&lam_s[w][0];
    unsigned zpw   = (unsigned)(size_t)&zp_s[w][4*l];
    unsigned zprd  = (unsigned)(size_t)&zp_s[(tid & 1) * 4][c];
    unsigned ysw   = (unsigned)(size_t)&y_s[c];
    unsigned ysr   = (unsigned)(size_t)&y_s[4*l];
    unsigned lamw  = (unsigned)(size_t)&lam_s[w][myrow];
    unsigned scw   = (unsigned)(size_t)&scr_s[tid];
    unsigned scrd  = (unsigned)(size_t)&scr_s[tid ^ 32];
    unsigned long long outa = (unsigned long long)(out + (size_t)bi * NN + c);
    float cr  = C[bi * NN + c];
    float sbv = 0.05f * Bv[bi * MM + 16*w + myrow];
    float lam = 0.f;
    int   cnt = 100;

    if (tid < 128) lam_s[tid >> 4][tid & 15] = 0.f;
    __syncthreads();

    asm volatile(
        // ---- load A tile into v[36:99] (row i, col j -> v(36+4i+j)) ----
        "global_load_dwordx4 v[36:39], %[a0], off\n\t"
        "global_load_dwordx4 v[40:43], %[a0], off offset:1024\n\t"
        "global_load_dwordx4 v[44:47], %[a0], off offset:2048\n\t"
        "global_load_dwordx4 v[48:51], %[a0], off offset:3072\n\t"
        "global_load_dwordx4 v[52:55], %[a4], off\n\t"
        "global_load_dwordx4 v[56:59], %[a4], off offset:1024\n\t"
        "global_load_dwordx4 v[60:63], %[a4], off offset:2048\n\t"
        "global_load_dwordx4 v[64:67], %[a4], off offset:3072\n\t"
        "global_load_dwordx4 v[68:71], %[a8], off\n\t"
        "global_load_dwordx4 v[72:75], %[a8], off offset:1024\n\t"
        "global_load_dwordx4 v[76:79], %[a8], off offset:2048\n\t"
        "global_load_dwordx4 v[80:83], %[a8], off offset:3072\n\t"
        "global_load_dwordx4 v[84:87], %[a12], off\n\t"
        "global_load_dwordx4 v[88:91], %[a12], off offset:1024\n\t"
        "global_load_dwordx4 v[92:95], %[a12], off offset:2048\n\t"
        "global_load_dwordx4 v[96:99], %[a12], off offset:3072\n\t"
        "s_waitcnt vmcnt(0)\n\t"
        ".LTOP%=:\n\t"
        // ---- P1: lamv[16] <- lam_s[w][0..15]; zp[4] in v[116:119] ----
        "ds_read_b128 v[100:103], %[lamrd]\n\t"
        "ds_read_b128 v[104:107], %[lamrd] offset:16\n\t"
        "ds_read_b128 v[108:111], %[lamrd] offset:32\n\t"
        "ds_read_b128 v[112:115], %[lamrd] offset:48\n\t"
        "s_waitcnt lgkmcnt(0)\n\t"
        "v_mul_f32 v116, v36, v100\n\t"
        "v_mul_f32 v117, v37, v100\n\t"
        "v_mul_f32 v118, v38, v100\n\t"
        "v_mul_f32 v119, v39, v100\n\t"
        "v_fmac_f32 v116, v40, v101\n\t"
        "v_fmac_f32 v117, v41, v101\n\t"
        "v_fmac_f32 v118, v42, v101\n\t"
        "v_fmac_f32 v119, v43, v101\n\t"
        "v_fmac_f32 v116, v44, v102\n\t"
        "v_fmac_f32 v117, v45, v102\n\t"
        "v_fmac_f32 v118, v46, v102\n\t"
        "v_fmac_f32 v119, v47, v102\n\t"
        "v_fmac_f32 v116, v48, v103\n\t"
        "v_fmac_f32 v117, v49, v103\n\t"
        "v_fmac_f32 v118, v50, v103\n\t"
        "v_fmac_f32 v119, v51, v103\n\t"
        "v_fmac_f32 v116, v52, v104\n\t"
        "v_fmac_f32 v117, v53, v104\n\t"
        "v_fmac_f32 v118, v54, v104\n\t"
        "v_fmac_f32 v119, v55, v104\n\t"
        "v_fmac_f32 v116, v56, v105\n\t"
        "v_fmac_f32 v117, v57, v105\n\t"
        "v_fmac_f32 v118, v58, v105\n\t"
        "v_fmac_f32 v119, v59, v105\n\t"
        "v_fmac_f32 v116, v60, v106\n\t"
        "v_fmac_f32 v117, v61, v106\n\t"
        "v_fmac_f32 v118, v62, v106\n\t"
        "v_fmac_f32 v119, v63, v106\n\t"
        "v_fmac_f32 v116, v64, v107\n\t"
        "v_fmac_f32 v117, v65, v107\n\t"
        "v_fmac_f32 v118, v66, v107\n\t"
        "v_fmac_f32 v119, v67, v107\n\t"
        "v_fmac_f32 v116, v68, v108\n\t"
        "v_fmac_f32 v117, v69, v108\n\t"
        "v_fmac_f32 v118, v70, v108\n\t"
        "v_fmac_f32 v119, v71, v108\n\t"
        "v_fmac_f32 v116, v72, v109\n\t"
        "v_fmac_f32 v117, v73, v109\n\t"
        "v_fmac_f32 v118, v74, v109\n\t"
        "v_fmac_f32 v119, v75, v109\n\t"
        "v_fmac_f32 v116, v76, v110\n\t"
        "v_fmac_f32 v117, v77, v110\n\t"
        "v_fmac_f32 v118, v78, v110\n\t"
        "v_fmac_f32 v119, v79, v110\n\t"
        "v_fmac_f32 v116, v80, v111\n\t"
        "v_fmac_f32 v117, v81, v111\n\t"
        "v_fmac_f32 v118, v82, v111\n\t"
        "v_fmac_f32 v119, v83, v111\n\t"
        "v_fmac_f32 v116, v84, v112\n\t"
        "v_fmac_f32 v117, v85, v112\n\t"
        "v_fmac_f32 v118, v86, v112\n\t"
        "v_fmac_f32 v119, v87, v112\n\t"
        "v_fmac_f32 v116, v88, v113\n\t"
        "v_fmac_f32 v117, v89, v113\n\t"
        "v_fmac_f32 v118, v90, v113\n\t"
        "v_fmac_f32 v119, v91, v113\n\t"
        "v_fmac_f32 v116, v92, v114\n\t"
        "v_fmac_f32 v117, v93, v114\n\t"
        "v_fmac_f32 v118, v94, v114\n\t"
        "v_fmac_f32 v119, v95, v114\n\t"
        "v_fmac_f32 v116, v96, v115\n\t"
        "v_fmac_f32 v117, v97, v115\n\t"
        "v_fmac_f32 v118, v98, v115\n\t"
        "v_fmac_f32 v119, v99, v115\n\t"
        "ds_write_b128 %[zpw], v[116:119]\n\t"
        "s_waitcnt lgkmcnt(0)\n\t"
        "s_barrier\n\t"
        // ---- P2: z over 8 waves (4 strided reads + xor1), sigmoid ----
        "ds_read_b32 v120, %[zprd]\n\t"
        "ds_read_b32 v121, %[zprd] offset:1040\n\t"
        "ds_read_b32 v122, %[zprd] offset:2080\n\t"
        "ds_read_b32 v123, %[zprd] offset:3120\n\t"
        "s_waitcnt lgkmcnt(0)\n\t"
        "v_add_f32 v120, v120, v121\n\t"
        "v_add_f32 v122, v122, v123\n\t"
        "v_add_f32 v120, v120, v122\n\t"
        "ds_swizzle_b32 v121, v120 offset:0x041F\n\t"
        "s_waitcnt lgkmcnt(0)\n\t"
        "v_add_f32 v120, v120, v121\n\t"
        "v_add_f32 v121, %[cr], v120\n\t"
        "v_mul_f32 v121, %[l2e], v121\n\t"
        "v_exp_f32 v121, v121\n\t"
        "s_nop 1\n\t"                      // TRANS hazard: exp result
        "v_add_f32 v121, 1.0, v121\n\t"
        "v_rcp_f32 v121, v121\n\t"
        "s_nop 1\n\t"                      // TRANS hazard: rcp result
        "s_cmp_eq_u32 %[cnt], 0\n\t"
        "s_cbranch_scc1 .LEXIT%=\n\t"
        // ---- P2b: publish y ----
        "ds_write_b32 %[ysw], v121\n\t"
        "s_waitcnt lgkmcnt(0)\n\t"
        "s_barrier\n\t"
        // ---- P3: p[16] = A y over my 4 cols (y4 in v[116:119]) ----
        "ds_read_b128 v[116:119], %[ysr]\n\t"
        "s_waitcnt lgkmcnt(0)\n\t"
        "v_mul_f32 v100, v36, v116\n\t"
        "v_mul_f32 v101, v40, v116\n\t"
        "v_mul_f32 v102, v44, v116\n\t"
        "v_mul_f32 v103, v48, v116\n\t"
        "v_mul_f32 v104, v52, v116\n\t"
        "v_mul_f32 v105, v56, v116\n\t"
        "v_mul_f32 v106, v60, v116\n\t"
        "v_mul_f32 v107, v64, v116\n\t"
        "v_mul_f32 v108, v68, v116\n\t"
        "v_mul_f32 v109, v72, v116\n\t"
        "v_mul_f32 v110, v76, v116\n\t"
        "v_mul_f32 v111, v80, v116\n\t"
        "v_mul_f32 v112, v84, v116\n\t"
        "v_mul_f32 v113, v88, v116\n\t"
        "v_mul_f32 v114, v92, v116\n\t"
        "v_mul_f32 v115, v96, v116\n\t"
        "v_fmac_f32 v100, v37, v117\n\t"
        "v_fmac_f32 v101, v41, v117\n\t"
        "v_fmac_f32 v102, v45, v117\n\t"
        "v_fmac_f32 v103, v49, v117\n\t"
        "v_fmac_f32 v104, v53, v117\n\t"
        "v_fmac_f32 v105, v57, v117\n\t"
        "v_fmac_f32 v106, v61, v117\n\t"
        "v_fmac_f32 v107, v65, v117\n\t"
        "v_fmac_f32 v108, v69, v117\n\t"
        "v_fmac_f32 v109, v73, v117\n\t"
        "v_fmac_f32 v110, v77, v117\n\t"
        "v_fmac_f32 v111, v81, v117\n\t"
        "v_fmac_f32 v112, v85, v117\n\t"
        "v_fmac_f32 v113, v89, v117\n\t"
        "v_fmac_f32 v114, v93, v117\n\t"
        "v_fmac_f32 v115, v97, v117\n\t"
        "v_fmac_f32 v100, v38, v118\n\t"
        "v_fmac_f32 v101, v42, v118\n\t"
        "v_fmac_f32 v102, v46, v118\n\t"
        "v_fmac_f32 v103, v50, v118\n\t"
        "v_fmac_f32 v104, v54, v118\n\t"
        "v_fmac_f32 v105, v58, v118\n\t"
        "v_fmac_f32 v106, v62, v118\n\t"
        "v_fmac_f32 v107, v66, v118\n\t"
        "v_fmac_f32 v108, v70, v118\n\t"
        "v_fmac_f32 v109, v74, v118\n\t"
        "v_fmac_f32 v110, v78, v118\n\t"
        "v_fmac_f32 v111, v82, v118\n\t"
        "v_fmac_f32 v112, v86, v118\n\t"
        "v_fmac_f32 v113, v90, v118\n\t"
        "v_fmac_f32 v114, v94, v118\n\t"
        "v_fmac_f32 v115, v98, v118\n\t"
        "v_fmac_f32 v100, v39, v119\n\t"
        "v_fmac_f32 v101, v43, v119\n\t"
        "v_fmac_f32 v102, v47, v119\n\t"
        "v_fmac_f32 v103, v51, v119\n\t"
        "v_fmac_f32 v104, v55, v119\n\t"
        "v_fmac_f32 v105, v59, v119\n\t"
        "v_fmac_f32 v106, v63, v119\n\t"
        "v_fmac_f32 v107, v67, v119\n\t"
        "v_fmac_f32 v108, v71, v119\n\t"
        "v_fmac_f32 v109, v75, v119\n\t"
        "v_fmac_f32 v110, v79, v119\n\t"
        "v_fmac_f32 v111, v83, v119\n\t"
        "v_fmac_f32 v112, v87, v119\n\t"
        "v_fmac_f32 v113, v91, v119\n\t"
        "v_fmac_f32 v114, v95, v119\n\t"
        "v_fmac_f32 v115, v99, v119\n\t"
        // ---- P4 reduce: round xor16 (keep/send via cndmask, two batches) ----
        "v_cndmask_b32 v120, v100, v108, %[mb4]\n\t"
        "v_cndmask_b32 v121, v101, v109, %[mb4]\n\t"
        "v_cndmask_b32 v122, v102, v110, %[mb4]\n\t"
        "v_cndmask_b32 v123, v103, v111, %[mb4]\n\t"
        "v_cndmask_b32 v124, v108, v100, %[mb4]\n\t"
        "v_cndmask_b32 v125, v109, v101, %[mb4]\n\t"
        "v_cndmask_b32 v126, v110, v102, %[mb4]\n\t"
        "v_cndmask_b32 v127, v111, v103, %[mb4]\n\t"
        "ds_swizzle_b32 v124, v124 offset:0x401F\n\t"
        "ds_swizzle_b32 v125, v125 offset:0x401F\n\t"
        "ds_swizzle_b32 v126, v126 offset:0x401F\n\t"
        "ds_swizzle_b32 v127, v127 offset:0x401F\n\t"
        "v_cndmask_b32 v116, v104, v112, %[mb4]\n\t"
        "v_cndmask_b32 v117, v105, v113, %[mb4]\n\t"
        "v_cndmask_b32 v118, v106, v114, %[mb4]\n\t"
        "v_cndmask_b32 v119, v107, v115, %[mb4]\n\t"
        "v_cndmask_b32 v108, v112, v104, %[mb4]\n\t"
        "v_cndmask_b32 v109, v113, v105, %[mb4]\n\t"
        "v_cndmask_b32 v110, v114, v106, %[mb4]\n\t"
        "v_cndmask_b32 v111, v115, v107, %[mb4]\n\t"
        "ds_swizzle_b32 v108, v108 offset:0x401F\n\t"
        "ds_swizzle_b32 v109, v109 offset:0x401F\n\t"
        "ds_swizzle_b32 v110, v110 offset:0x401F\n\t"
        "ds_swizzle_b32 v111, v111 offset:0x401F\n\t"
        "s_waitcnt lgkmcnt(0)\n\t"
        "v_add_f32 v100, v120, v124\n\t"
        "v_add_f32 v101, v121, v125\n\t"
        "v_add_f32 v102, v122, v126\n\t"
        "v_add_f32 v103, v123, v127\n\t"
        "v_add_f32 v104, v116, v108\n\t"
        "v_add_f32 v105, v117, v109\n\t"
        "v_add_f32 v106, v118, v110\n\t"
        "v_add_f32 v107, v119, v111\n\t"
        // ---- round xor8 ----
        "v_cndmask_b32 v120, v100, v104, %[mb3]\n\t"
        "v_cndmask_b32 v121, v101, v105, %[mb3]\n\t"
        "v_cndmask_b32 v122, v102, v106, %[mb3]\n\t"
        "v_cndmask_b32 v123, v103, v107, %[mb3]\n\t"
        "v_cndmask_b32 v124, v104, v100, %[mb3]\n\t"
        "v_cndmask_b32 v125, v105, v101, %[mb3]\n\t"
        "v_cndmask_b32 v126, v106, v102, %[mb3]\n\t"
        "v_cndmask_b32 v127, v107, v103, %[mb3]\n\t"
        "ds_swizzle_b32 v124, v124 offset:0x201F\n\t"
        "ds_swizzle_b32 v125, v125 offset:0x201F\n\t"
        "ds_swizzle_b32 v126, v126 offset:0x201F\n\t"
        "ds_swizzle_b32 v127, v127 offset:0x201F\n\t"
        "s_waitcnt lgkmcnt(0)\n\t"
        "v_add_f32 v100, v120, v124\n\t"
        "v_add_f32 v101, v121, v125\n\t"
        "v_add_f32 v102, v122, v126\n\t"
        "v_add_f32 v103, v123, v127\n\t"
        // ---- round xor4 ----
        "v_cndmask_b32 v120, v100, v102, %[mb2]\n\t"
        "v_cndmask_b32 v121, v101, v103, %[mb2]\n\t"
        "v_cndmask_b32 v122, v102, v100, %[mb2]\n\t"
        "v_cndmask_b32 v123, v103, v101, %[mb2]\n\t"
        "ds_swizzle_b32 v122, v122 offset:0x101F\n\t"
        "ds_swizzle_b32 v123, v123 offset:0x101F\n\t"
        "s_waitcnt lgkmcnt(0)\n\t"
        "v_add_f32 v100, v120, v122\n\t"
        "v_add_f32 v101, v121, v123\n\t"
        // ---- round xor2 ----
        "v_cndmask_b32 v120, v100, v101, %[mb1]\n\t"
        "v_cndmask_b32 v121, v101, v100, %[mb1]\n\t"
        "ds_swizzle_b32 v121, v121 offset:0x081F\n\t"
        "s_waitcnt lgkmcnt(0)\n\t"
        "v_add_f32 v100, v120, v121\n\t"
        // ---- butterfly xor1 ----
        "ds_swizzle_b32 v101, v100 offset:0x041F\n\t"
        "s_waitcnt lgkmcnt(0)\n\t"
        "v_add_f32 v100, v100, v101\n\t"
        // ---- butterfly xor32 via LDS scratch (in-wave ordered) ----
        "ds_write_b32 %[scw], v100\n\t"
        "s_waitcnt lgkmcnt(0)\n\t"
        "ds_read_b32 v101, %[scrd]\n\t"
        "s_waitcnt lgkmcnt(0)\n\t"
        "v_add_f32 v100, v100, v101\n\t"
        // ---- lambda update + publish ----
        "v_fmac_f32 %[lam], %[step], v100\n\t"
        "v_add_f32 %[lam], %[sb], %[lam]\n\t"
        "v_max_f32 %[lam], 0, %[lam]\n\t"
        "ds_write_b32 %[lamw], %[lam]\n\t"
        "s_waitcnt lgkmcnt(0)\n\t"
        "s_sub_u32 %[cnt], %[cnt], 1\n\t"
        "s_branch .LTOP%=\n\t"
        ".LEXIT%=:\n\t"
        "global_store_dword %[outa], v121, off\n\t"
        "s_waitcnt vmcnt(0)\n\t"
        : [lam] "+v"(lam), [cnt] "+s"(cnt)
        : [a0] "v"(a0), [a4] "v"(a4), [a8] "v"(a8), [a12] "v"(a12),
          [lamrd] "v"(lamrd), [zpw] "v"(zpw), [zprd] "v"(zprd),
          [ysw] "v"(ysw), [ysr] "v"(ysr), [lamw] "v"(lamw),
          [scw] "v"(scw), [scrd] "v"(scrd), [outa] "v"(outa),
          [cr] "v"(cr), [sb] "v"(sbv),
          [step] "s"(0.05f), [l2e] "s"(1.4426950408889634f),
          [mb4] "s"(0xFFFF0000FFFF0000ull), [mb3] "s"(0xFF00FF00FF00FF00ull),
          [mb2] "s"(0xF0F0F0F0F0F0F0F0ull), [mb1] "s"(0xCCCCCCCCCCCCCCCCull)
        : "memory", "scc",
          "v36","v37","v38","v39","v40","v41","v42","v43","v44","v45",
          "v46","v47","v48","v49","v50","v51","v52","v53","v54","v55",
          "v56","v57","v58","v59","v60","v61","v62","v63","v64","v65",
          "v66","v67","v68","v69","v70","v71","v72","v73","v74","v75",
          "v76","v77","v78","v79","v80","v81","v82","v83","v84","v85",
          "v86","v87","v88","v89","v90","v91","v92","v93","v94","v95",
          "v96","v97","v98","v99","v100","v101","v102","v103","v104",
          "v105","v106","v107","v108","v109","v110","v111","v112","v113",
          "v114","v115","v116","v117","v118","v119","v120","v121","v122",
          "v123","v124","v125","v126","v127");

    if (tid == 0) out[(size_t)BB * NN + bi] = 0.0f;  // status[bi] = int32 0
}

extern "C" void kernel_launch(void* const* d_in, const int* in_sizes, int n_in,
                              void* d_out, int out_size, void* d_ws, size_t ws_size,
                              hipStream_t stream) {
    const float* A  = (const float*)d_in[0];  // [2048,128,256]
    const float* Bv = (const float*)d_in[1];  // [2048,128]
    const float* C  = (const float*)d_in[2];  // [2048,256]
    float* out = (float*)d_out;               // y [2048,256] f32 ++ status [2048]

    cvx_dual_ascent<<<dim3(BB), dim3(512), 0, stream>>>(A, Bv, C, out);
}